// Round 1
// baseline (281.706 us; speedup 1.0000x reference)
//
#include <hip/hip_runtime.h>
#include <math.h>

// Problem constants (from reference)
#define NN 10000
#define INF 512
#define HF  512
#define OF  64
#define NE  163840

// ---------------- graph preprocessing ----------------

__global__ void k_zero_int(int* __restrict__ p, int n) {
    int i = blockIdx.x * blockDim.x + threadIdx.x;
    if (i < n) p[i] = 0;
}

__global__ void k_count(const int* __restrict__ dst, int* __restrict__ cnt, int E) {
    int e = blockIdx.x * blockDim.x + threadIdx.x;
    if (e < E) atomicAdd(&cnt[dst[e]], 1);
}

// Single-block exclusive scan over N counts -> row_start[0..N], cursor copy, dinv = rsqrt(cnt+1)
__global__ __launch_bounds__(1024) void k_scan(const int* __restrict__ cnt,
                                               int* __restrict__ row_start,
                                               int* __restrict__ cursor,
                                               float* __restrict__ dinv, int n) {
    __shared__ int part[1024];
    int t = threadIdx.x;
    const int CH = (n + 1023) >> 10;      // 10 for n=10000
    int begin = t * CH;
    int end = begin + CH;
    if (begin > n) begin = n;
    if (end > n) end = n;
    int s = 0;
    for (int i = begin; i < end; i++) s += cnt[i];
    part[t] = s;
    __syncthreads();
    // Hillis-Steele inclusive scan over 1024 partials
    for (int off = 1; off < 1024; off <<= 1) {
        int v = part[t];
        int add = (t >= off) ? part[t - off] : 0;
        __syncthreads();
        part[t] = v + add;
        __syncthreads();
    }
    int excl = (t == 0) ? 0 : part[t - 1];
    for (int i = begin; i < end; i++) {
        row_start[i] = excl;
        cursor[i] = excl;
        int c = cnt[i];
        excl += c;
        dinv[i] = rsqrtf((float)(c + 1));   // +1 self-loop; always > 0
    }
    if (t == 1023) row_start[n] = part[1023];
}

__global__ void k_fill(const int* __restrict__ src, const int* __restrict__ dst,
                       const float* __restrict__ dinv, int* __restrict__ cursor,
                       int* __restrict__ csr_src, float* __restrict__ csr_w, int E) {
    int e = blockIdx.x * blockDim.x + threadIdx.x;
    if (e >= E) return;
    int s = src[e], d = dst[e];
    int p = atomicAdd(&cursor[d], 1);
    csr_src[p] = s;
    csr_w[p] = dinv[s] * dinv[d];
}

// ---------------- GEMM: X[N,512] @ W[512,512] -> Y[N,512] ----------------
// 16 rows/block, 256 threads: thread = (colq = (tid&127)*4, rbase = (tid>>7)*8)
__global__ __launch_bounds__(256) void k_gemm512(const float* __restrict__ X,
                                                 const float* __restrict__ W,
                                                 float* __restrict__ Y) {
    __shared__ float xs[16 * 512];        // 32 KB
    int tid = threadIdx.x;
    int row0 = blockIdx.x * 16;
    const float4* Xv = (const float4*)(X + row0 * 512);
    float4* xsv = (float4*)xs;
#pragma unroll
    for (int i = 0; i < 8; i++) xsv[i * 256 + tid] = Xv[i * 256 + tid];
    __syncthreads();
    int colq = (tid & 127) * 4;
    int rbase = (tid >> 7) * 8;
    float4 acc[8];
#pragma unroll
    for (int r = 0; r < 8; r++) acc[r] = make_float4(0.f, 0.f, 0.f, 0.f);
    for (int k = 0; k < 512; k += 4) {
        float4 xr[8];
#pragma unroll
        for (int r = 0; r < 8; r++) xr[r] = *(const float4*)&xs[(rbase + r) * 512 + k];
#pragma unroll
        for (int ki = 0; ki < 4; ki++) {
            float4 w = *(const float4*)&W[(k + ki) * 512 + colq];
#pragma unroll
            for (int r = 0; r < 8; r++) {
                float xv = (ki == 0) ? xr[r].x : (ki == 1) ? xr[r].y : (ki == 2) ? xr[r].z : xr[r].w;
                acc[r].x += xv * w.x;
                acc[r].y += xv * w.y;
                acc[r].z += xv * w.z;
                acc[r].w += xv * w.w;
            }
        }
    }
#pragma unroll
    for (int r = 0; r < 8; r++)
        *(float4*)&Y[(row0 + rbase + r) * 512 + colq] = acc[r];
}

// ---------------- GEMM: X[N,512] @ W[512,64] -> Y[N,64] ----------------
__global__ __launch_bounds__(256) void k_gemm64(const float* __restrict__ X,
                                                const float* __restrict__ W,
                                                float* __restrict__ Y) {
    __shared__ float xs[16 * 512];
    int tid = threadIdx.x;
    int row0 = blockIdx.x * 16;
    const float4* Xv = (const float4*)(X + row0 * 512);
    float4* xsv = (float4*)xs;
#pragma unroll
    for (int i = 0; i < 8; i++) xsv[i * 256 + tid] = Xv[i * 256 + tid];
    __syncthreads();
    int col = tid & 63;
    int rbase = (tid >> 6) * 4;
    float acc[4] = {0.f, 0.f, 0.f, 0.f};
    for (int k = 0; k < 512; k += 4) {
        float4 xr[4];
#pragma unroll
        for (int r = 0; r < 4; r++) xr[r] = *(const float4*)&xs[(rbase + r) * 512 + k];
#pragma unroll
        for (int ki = 0; ki < 4; ki++) {
            float w = W[(k + ki) * 64 + col];
#pragma unroll
            for (int r = 0; r < 4; r++) {
                float xv = (ki == 0) ? xr[r].x : (ki == 1) ? xr[r].y : (ki == 2) ? xr[r].z : xr[r].w;
                acc[r] += xv * w;
            }
        }
    }
#pragma unroll
    for (int r = 0; r < 4; r++)
        Y[(row0 + rbase + r) * 64 + col] = acc[r];
}

// ---------------- aggregate layer 1 (512 feats) + bias + relu ----------------
__global__ __launch_bounds__(256) void k_agg1(const float* __restrict__ Hm,
                                              const int* __restrict__ row_start,
                                              const int* __restrict__ csr_src,
                                              const float* __restrict__ csr_w,
                                              const float* __restrict__ dinv,
                                              const float* __restrict__ b,
                                              float* __restrict__ A) {
    int v = blockIdx.x;
    int t = threadIdx.x;
    float dv = dinv[v];
    float sw = dv * dv;                    // self-loop norm
    float a0 = Hm[v * 512 + t] * sw;
    float a1 = Hm[v * 512 + 256 + t] * sw;
    int beg = row_start[v], end = row_start[v + 1];
    for (int j = beg; j < end; j++) {
        int s = csr_src[j];
        float w = csr_w[j];
        a0 += Hm[s * 512 + t] * w;
        a1 += Hm[s * 512 + 256 + t] * w;
    }
    a0 += b[t];
    a1 += b[256 + t];
    A[v * 512 + t] = a0 > 0.f ? a0 : 0.f;
    A[v * 512 + 256 + t] = a1 > 0.f ? a1 : 0.f;
}

// ---------------- aggregate layer 2 (64 feats) + bias + log_softmax ----------------
__global__ __launch_bounds__(64) void k_agg2_lsm(const float* __restrict__ Hm,
                                                 const int* __restrict__ row_start,
                                                 const int* __restrict__ csr_src,
                                                 const float* __restrict__ csr_w,
                                                 const float* __restrict__ dinv,
                                                 const float* __restrict__ b,
                                                 float* __restrict__ out) {
    int v = blockIdx.x;
    int t = threadIdx.x;
    float dv = dinv[v];
    float acc = Hm[v * 64 + t] * dv * dv;
    int beg = row_start[v], end = row_start[v + 1];
    for (int j = beg; j < end; j++) {
        int s = csr_src[j];
        float w = csr_w[j];
        acc += Hm[s * 64 + t] * w;
    }
    float h = acc + b[t];
    out[v * 64 + t] = h;                   // output 0: h
    // 64-lane max
    float m = h;
#pragma unroll
    for (int off = 32; off >= 1; off >>= 1) m = fmaxf(m, __shfl_xor(m, off, 64));
    float e = expf(h - m);
    float ssum = e;
#pragma unroll
    for (int off = 32; off >= 1; off >>= 1) ssum += __shfl_xor(ssum, off, 64);
    out[NN * OF + v * 64 + t] = h - m - logf(ssum);  // output 1: log_softmax
}

// ---------------- launch ----------------

extern "C" void kernel_launch(void* const* d_in, const int* in_sizes, int n_in,
                              void* d_out, int out_size, void* d_ws, size_t ws_size,
                              hipStream_t stream) {
    const float* x  = (const float*)d_in[0];
    const int*   ei = (const int*)d_in[1];
    const float* W1 = (const float*)d_in[2];
    const float* b1 = (const float*)d_in[3];
    const float* W2 = (const float*)d_in[4];
    const float* b2 = (const float*)d_in[5];
    float* out = (float*)d_out;

    const int E = in_sizes[1] / 2;       // 163840
    const int* src = ei;
    const int* dst = ei + E;

    // workspace carve (256B aligned)
    char* w = (char*)d_ws;
    auto carve = [&](size_t bytes) {
        char* p = w;
        w += (bytes + 255) & ~size_t(255);
        return p;
    };
    float* h1      = (float*)carve((size_t)NN * 512 * 4);   // 20.48 MB
    float* a1      = (float*)carve((size_t)NN * 512 * 4);   // 20.48 MB
    float* h2      = (float*)carve((size_t)NN * 64 * 4);    // 2.56 MB
    int*   cnt     = (int*)carve((size_t)NN * 4);
    int*   rstart  = (int*)carve((size_t)(NN + 1) * 4);
    int*   cursor  = (int*)carve((size_t)NN * 4);
    int*   csr_src = (int*)carve((size_t)NE * 4);
    float* csr_w   = (float*)carve((size_t)NE * 4);
    float* dinv    = (float*)carve((size_t)NN * 4);
    (void)ws_size;

    k_zero_int<<<(NN + 255) / 256, 256, 0, stream>>>(cnt, NN);
    k_count<<<(E + 255) / 256, 256, 0, stream>>>(dst, cnt, E);
    k_scan<<<1, 1024, 0, stream>>>(cnt, rstart, cursor, dinv, NN);
    k_fill<<<(E + 255) / 256, 256, 0, stream>>>(src, dst, dinv, cursor, csr_src, csr_w, E);

    k_gemm512<<<NN / 16, 256, 0, stream>>>(x, W1, h1);
    k_agg1<<<NN, 256, 0, stream>>>(h1, rstart, csr_src, csr_w, dinv, b1, a1);
    k_gemm64<<<NN / 16, 256, 0, stream>>>(a1, W2, h2);
    k_agg2_lsm<<<NN, 64, 0, stream>>>(h2, rstart, csr_src, csr_w, dinv, b2, out);
}

// Round 2
// 227.628 us; speedup vs baseline: 1.2376x; 1.2376x over previous
//
#include <hip/hip_runtime.h>
#include <math.h>

// Problem constants (from reference)
#define NN 10000
#define INF 512
#define HF  512
#define OF  64
#define NE  163840

typedef __attribute__((ext_vector_type(8))) short bf16x8_t;   // 8 bf16 = 4 VGPRs
typedef __attribute__((ext_vector_type(4))) float f32x4_t;    // 4 fp32 acc

__device__ inline ushort f2bf(float f) {
    unsigned u = __float_as_uint(f);
    u = (u + 0x7FFF + ((u >> 16) & 1)) >> 16;   // RNE
    return (ushort)u;
}

// ---------------- graph preprocessing ----------------

__global__ void k_zero_int(int* __restrict__ p, int n) {
    int i = blockIdx.x * blockDim.x + threadIdx.x;
    if (i < n) p[i] = 0;
}

__global__ void k_count(const int* __restrict__ dst, int* __restrict__ cnt, int E) {
    int e = blockIdx.x * blockDim.x + threadIdx.x;
    if (e < E) atomicAdd(&cnt[dst[e]], 1);
}

// Single-block exclusive scan over N counts -> row_start[0..N], cursor copy, dinv = rsqrt(cnt+1)
__global__ __launch_bounds__(1024) void k_scan(const int* __restrict__ cnt,
                                               int* __restrict__ row_start,
                                               int* __restrict__ cursor,
                                               float* __restrict__ dinv, int n) {
    __shared__ int part[1024];
    int t = threadIdx.x;
    const int CH = (n + 1023) >> 10;
    int begin = t * CH;
    int end = begin + CH;
    if (begin > n) begin = n;
    if (end > n) end = n;
    int s = 0;
    for (int i = begin; i < end; i++) s += cnt[i];
    part[t] = s;
    __syncthreads();
    for (int off = 1; off < 1024; off <<= 1) {
        int v = part[t];
        int add = (t >= off) ? part[t - off] : 0;
        __syncthreads();
        part[t] = v + add;
        __syncthreads();
    }
    int excl = (t == 0) ? 0 : part[t - 1];
    for (int i = begin; i < end; i++) {
        row_start[i] = excl;
        cursor[i] = excl;
        int c = cnt[i];
        excl += c;
        dinv[i] = rsqrtf((float)(c + 1));   // +1 self-loop; always > 0
    }
    if (t == 1023) row_start[n] = part[1023];
}

__global__ void k_fill(const int* __restrict__ src, const int* __restrict__ dst,
                       const float* __restrict__ dinv, int* __restrict__ cursor,
                       int* __restrict__ csr_src, float* __restrict__ csr_w, int E) {
    int e = blockIdx.x * blockDim.x + threadIdx.x;
    if (e >= E) return;
    int s = src[e], d = dst[e];
    int p = atomicAdd(&cursor[d], 1);
    csr_src[p] = s;
    csr_w[p] = dinv[s] * dinv[d];
}

// ---------------- bf16 conversions ----------------

// x [NN,512] fp32 -> Xb bf16 (flat), 4 elems/thread
__global__ __launch_bounds__(256) void k_cvt_x(const float* __restrict__ X,
                                               ushort* __restrict__ Xb) {
    int i = blockIdx.x * blockDim.x + threadIdx.x;      // float4 index
    float4 v = ((const float4*)X)[i];
    ushort4 o;
    o.x = f2bf(v.x); o.y = f2bf(v.y); o.z = f2bf(v.z); o.w = f2bf(v.w);
    ((ushort4*)Xb)[i] = o;
}

// W [512,512] fp32 row-major (k-major) -> WT bf16 [n][k]
__global__ __launch_bounds__(256) void k_cvt_wT(const float* __restrict__ W,
                                                ushort* __restrict__ WT) {
    __shared__ float t[32][33];
    int tx = threadIdx.x;        // 0..31
    int ty = threadIdx.y;        // 0..7
    int k0 = blockIdx.x * 32;
    int n0 = blockIdx.y * 32;
#pragma unroll
    for (int i = 0; i < 4; i++)
        t[ty + i * 8][tx] = W[(k0 + ty + i * 8) * 512 + n0 + tx];
    __syncthreads();
#pragma unroll
    for (int i = 0; i < 4; i++)
        WT[(n0 + ty + i * 8) * 512 + k0 + tx] = f2bf(t[tx][ty + i * 8]);
}

// ---------------- MFMA GEMM: Xb[NN,512]bf16 @ WT[512,512]bf16(T) -> Y[NN,512]f32 ----------
// Block tile 64x128, BK=64, 4 waves in 2x2, wave tile 32x64 (2x4 of 16x16).
// LDS rows padded +8 bf16 (stride 72 elem = 144 B): 16B-aligned, ~2-way bank alias (free).
#define LDA 72
__global__ __launch_bounds__(256) void k_gemm_mfma(const ushort* __restrict__ Xb,
                                                   const ushort* __restrict__ WT,
                                                   float* __restrict__ Y) {
    __shared__ ushort As[64 * LDA];     //  9.2 KB
    __shared__ ushort Bs[128 * LDA];    // 18.4 KB
    int tid = threadIdx.x;
    int lane = tid & 63;
    int wave = tid >> 6;
    int m = lane & 15;
    int q = lane >> 4;                  // 0..3
    int wr = wave >> 1;                 // 0..1 row half
    int wc = wave & 1;                  // 0..1 col half
    int row0 = blockIdx.x * 64;
    int col0 = blockIdx.y * 128;

    f32x4_t acc[2][4];
#pragma unroll
    for (int r = 0; r < 2; r++)
#pragma unroll
        for (int c = 0; c < 4; c++) acc[r][c] = (f32x4_t){0.f, 0.f, 0.f, 0.f};

    int srow = tid >> 3;                // 0..31
    int skk = (tid & 7) * 8;            // 0..56

    for (int kb = 0; kb < 512; kb += 64) {
        // stage A: 64 rows x 64 k
#pragma unroll
        for (int c_ = 0; c_ < 2; c_++) {
            int row = srow + c_ * 32;
            int grow = row0 + row;
            bf16x8_t v = {0, 0, 0, 0, 0, 0, 0, 0};
            if (grow < NN)
                v = *(const bf16x8_t*)(Xb + (size_t)grow * 512 + kb + skk);
            *(bf16x8_t*)(As + row * LDA + skk) = v;
        }
        // stage B: 128 n-rows x 64 k (WT is [n][k])
#pragma unroll
        for (int c_ = 0; c_ < 4; c_++) {
            int n = srow + c_ * 32;
            bf16x8_t v = *(const bf16x8_t*)(WT + (size_t)(col0 + n) * 512 + kb + skk);
            *(bf16x8_t*)(Bs + n * LDA + skk) = v;
        }
        __syncthreads();
#pragma unroll
        for (int kc = 0; kc < 2; kc++) {
            bf16x8_t a[2], b[4];
#pragma unroll
            for (int r = 0; r < 2; r++)
                a[r] = *(const bf16x8_t*)(As + (wr * 32 + r * 16 + m) * LDA + kc * 32 + q * 8);
#pragma unroll
            for (int c = 0; c < 4; c++)
                b[c] = *(const bf16x8_t*)(Bs + (wc * 64 + c * 16 + m) * LDA + kc * 32 + q * 8);
#pragma unroll
            for (int r = 0; r < 2; r++)
#pragma unroll
                for (int c = 0; c < 4; c++)
                    acc[r][c] = __builtin_amdgcn_mfma_f32_16x16x32_bf16(a[r], b[c], acc[r][c], 0, 0, 0);
        }
        __syncthreads();
    }
    // store: D row = q*4+reg, col = m  (verified C/D layout)
#pragma unroll
    for (int r = 0; r < 2; r++) {
#pragma unroll
        for (int c = 0; c < 4; c++) {
#pragma unroll
            for (int reg = 0; reg < 4; reg++) {
                int row = row0 + wr * 32 + r * 16 + q * 4 + reg;
                int col = col0 + wc * 64 + c * 16 + m;
                if (row < NN) Y[(size_t)row * 512 + col] = acc[r][c][reg];
            }
        }
    }
}

// ---------------- GEMM: X[N,512] @ W[512,64] -> Y[N,64] (fp32 vector) ----------------
__global__ __launch_bounds__(256) void k_gemm64(const float* __restrict__ X,
                                                const float* __restrict__ W,
                                                float* __restrict__ Y) {
    __shared__ float xs[16 * 512];
    int tid = threadIdx.x;
    int row0 = blockIdx.x * 16;
    const float4* Xv = (const float4*)(X + row0 * 512);
    float4* xsv = (float4*)xs;
#pragma unroll
    for (int i = 0; i < 8; i++) xsv[i * 256 + tid] = Xv[i * 256 + tid];
    __syncthreads();
    int col = tid & 63;
    int rbase = (tid >> 6) * 4;
    float acc[4] = {0.f, 0.f, 0.f, 0.f};
    for (int k = 0; k < 512; k += 4) {
        float4 xr[4];
#pragma unroll
        for (int r = 0; r < 4; r++) xr[r] = *(const float4*)&xs[(rbase + r) * 512 + k];
#pragma unroll
        for (int ki = 0; ki < 4; ki++) {
            float w = W[(k + ki) * 64 + col];
#pragma unroll
            for (int r = 0; r < 4; r++) {
                float xv = (ki == 0) ? xr[r].x : (ki == 1) ? xr[r].y : (ki == 2) ? xr[r].z : xr[r].w;
                acc[r] += xv * w;
            }
        }
    }
#pragma unroll
    for (int r = 0; r < 4; r++)
        Y[(row0 + rbase + r) * 64 + col] = acc[r];
}

// ---------------- aggregate layer 1 (512 feats) + bias + relu ----------------
__global__ __launch_bounds__(256) void k_agg1(const float* __restrict__ Hm,
                                              const int* __restrict__ row_start,
                                              const int* __restrict__ csr_src,
                                              const float* __restrict__ csr_w,
                                              const float* __restrict__ dinv,
                                              const float* __restrict__ b,
                                              float* __restrict__ A) {
    int v = blockIdx.x;
    int t = threadIdx.x;
    float dv = dinv[v];
    float sw = dv * dv;                    // self-loop norm
    float a0 = Hm[v * 512 + t] * sw;
    float a1 = Hm[v * 512 + 256 + t] * sw;
    int beg = row_start[v], end = row_start[v + 1];
    for (int j = beg; j < end; j++) {
        int s = csr_src[j];
        float w = csr_w[j];
        a0 += Hm[s * 512 + t] * w;
        a1 += Hm[s * 512 + 256 + t] * w;
    }
    a0 += b[t];
    a1 += b[256 + t];
    A[v * 512 + t] = a0 > 0.f ? a0 : 0.f;
    A[v * 512 + 256 + t] = a1 > 0.f ? a1 : 0.f;
}

// ---------------- aggregate layer 2 (64 feats) + bias + log_softmax ----------------
__global__ __launch_bounds__(64) void k_agg2_lsm(const float* __restrict__ Hm,
                                                 const int* __restrict__ row_start,
                                                 const int* __restrict__ csr_src,
                                                 const float* __restrict__ csr_w,
                                                 const float* __restrict__ dinv,
                                                 const float* __restrict__ b,
                                                 float* __restrict__ out) {
    int v = blockIdx.x;
    int t = threadIdx.x;
    float dv = dinv[v];
    float acc = Hm[v * 64 + t] * dv * dv;
    int beg = row_start[v], end = row_start[v + 1];
    for (int j = beg; j < end; j++) {
        int s = csr_src[j];
        float w = csr_w[j];
        acc += Hm[s * 64 + t] * w;
    }
    float h = acc + b[t];
    out[v * 64 + t] = h;                   // output 0: h
    float m = h;
#pragma unroll
    for (int off = 32; off >= 1; off >>= 1) m = fmaxf(m, __shfl_xor(m, off, 64));
    float e = expf(h - m);
    float ssum = e;
#pragma unroll
    for (int off = 32; off >= 1; off >>= 1) ssum += __shfl_xor(ssum, off, 64);
    out[NN * OF + v * 64 + t] = h - m - logf(ssum);  // output 1: log_softmax
}

// ---------------- launch ----------------

extern "C" void kernel_launch(void* const* d_in, const int* in_sizes, int n_in,
                              void* d_out, int out_size, void* d_ws, size_t ws_size,
                              hipStream_t stream) {
    const float* x  = (const float*)d_in[0];
    const int*   ei = (const int*)d_in[1];
    const float* W1 = (const float*)d_in[2];
    const float* b1 = (const float*)d_in[3];
    const float* W2 = (const float*)d_in[4];
    const float* b2 = (const float*)d_in[5];
    float* out = (float*)d_out;

    const int E = in_sizes[1] / 2;       // 163840
    const int* src = ei;
    const int* dst = ei + E;

    // workspace carve (256B aligned)
    char* w = (char*)d_ws;
    auto carve = [&](size_t bytes) {
        char* p = w;
        w += (bytes + 255) & ~size_t(255);
        return p;
    };
    float* h1      = (float*)carve((size_t)NN * 512 * 4);   // 20.48 MB
    float* a1      = (float*)carve((size_t)NN * 512 * 4);   // 20.48 MB (Xb aliased here)
    float* h2      = (float*)carve((size_t)NN * 64 * 4);    // 2.56 MB
    int*   cnt     = (int*)carve((size_t)NN * 4);
    int*   rstart  = (int*)carve((size_t)(NN + 1) * 4);
    int*   cursor  = (int*)carve((size_t)NN * 4);
    int*   csr_src = (int*)carve((size_t)NE * 4);
    float* csr_w   = (float*)carve((size_t)NE * 4);
    float* dinv    = (float*)carve((size_t)NN * 4);
    ushort* WTb    = (ushort*)carve((size_t)512 * 512 * 2); // 0.5 MB
    (void)ws_size;

    // Xb aliases a1: Xb consumed by k_gemm_mfma, a1 first written later by k_agg1.
    ushort* Xb = (ushort*)a1;

    k_zero_int<<<(NN + 255) / 256, 256, 0, stream>>>(cnt, NN);
    k_count<<<(E + 255) / 256, 256, 0, stream>>>(dst, cnt, E);
    k_scan<<<1, 1024, 0, stream>>>(cnt, rstart, cursor, dinv, NN);
    k_fill<<<(E + 255) / 256, 256, 0, stream>>>(src, dst, dinv, cursor, csr_src, csr_w, E);

    k_cvt_x<<<(NN * 512 / 4 + 255) / 256, 256, 0, stream>>>(x, Xb);
    k_cvt_wT<<<dim3(16, 16), dim3(32, 8), 0, stream>>>(W1, WTb);
    k_gemm_mfma<<<dim3((NN + 63) / 64, 4), 256, 0, stream>>>(Xb, WTb, h1);

    k_agg1<<<NN, 256, 0, stream>>>(h1, rstart, csr_src, csr_w, dinv, b1, a1);
    k_gemm64<<<NN / 16, 256, 0, stream>>>(a1, W2, h2);
    k_agg2_lsm<<<NN, 64, 0, stream>>>(h2, rstart, csr_src, csr_w, dinv, b2, out);
}

// Round 3
// 216.966 us; speedup vs baseline: 1.2984x; 1.0491x over previous
//
#include <hip/hip_runtime.h>
#include <math.h>

// Problem constants (from reference)
#define NN 10000
#define INF 512
#define HF  512
#define OF  64
#define NE  163840

typedef __attribute__((ext_vector_type(8))) short bf16x8_t;   // 8 bf16 = 4 VGPRs
typedef __attribute__((ext_vector_type(4))) float f32x4_t;    // 4 fp32 acc

__device__ inline ushort f2bf(float f) {
    unsigned u = __float_as_uint(f);
    u = (u + 0x7FFF + ((u >> 16) & 1)) >> 16;   // RNE
    return (ushort)u;
}
__device__ inline float bf2f(ushort u) {
    return __uint_as_float(((unsigned)u) << 16);
}

// ---------------- graph preprocessing ----------------

__global__ void k_zero_int(int* __restrict__ p, int n) {
    int i = blockIdx.x * blockDim.x + threadIdx.x;
    if (i < n) p[i] = 0;
}

__global__ void k_count(const int* __restrict__ dst, int* __restrict__ cnt, int E) {
    int e = blockIdx.x * blockDim.x + threadIdx.x;
    if (e < E) atomicAdd(&cnt[dst[e]], 1);
}

// Single-block exclusive scan over N counts -> row_start[0..N], cursor copy, dinv = rsqrt(cnt+1)
__global__ __launch_bounds__(1024) void k_scan(const int* __restrict__ cnt,
                                               int* __restrict__ row_start,
                                               int* __restrict__ cursor,
                                               float* __restrict__ dinv, int n) {
    __shared__ int part[1024];
    int t = threadIdx.x;
    const int CH = (n + 1023) >> 10;
    int begin = t * CH;
    int end = begin + CH;
    if (begin > n) begin = n;
    if (end > n) end = n;
    int s = 0;
    for (int i = begin; i < end; i++) s += cnt[i];
    part[t] = s;
    __syncthreads();
    for (int off = 1; off < 1024; off <<= 1) {
        int v = part[t];
        int add = (t >= off) ? part[t - off] : 0;
        __syncthreads();
        part[t] = v + add;
        __syncthreads();
    }
    int excl = (t == 0) ? 0 : part[t - 1];
    for (int i = begin; i < end; i++) {
        row_start[i] = excl;
        cursor[i] = excl;
        int c = cnt[i];
        excl += c;
        dinv[i] = rsqrtf((float)(c + 1));   // +1 self-loop; always > 0
    }
    if (t == 1023) row_start[n] = part[1023];
}

__global__ void k_fill(const int* __restrict__ src, const int* __restrict__ dst,
                       const float* __restrict__ dinv, int* __restrict__ cursor,
                       int* __restrict__ csr_src, float* __restrict__ csr_w, int E) {
    int e = blockIdx.x * blockDim.x + threadIdx.x;
    if (e >= E) return;
    int s = src[e], d = dst[e];
    int p = atomicAdd(&cursor[d], 1);
    csr_src[p] = s;
    csr_w[p] = dinv[s] * dinv[d];
}

// ---------------- bf16 conversions ----------------

// X fp32 flat -> Xb bf16 flat, 4 elems/thread
__global__ __launch_bounds__(256) void k_cvt_x(const float* __restrict__ X,
                                               ushort* __restrict__ Xb) {
    int i = blockIdx.x * blockDim.x + threadIdx.x;      // float4 index
    float4 v = ((const float4*)X)[i];
    ushort4 o;
    o.x = f2bf(v.x); o.y = f2bf(v.y); o.z = f2bf(v.z); o.w = f2bf(v.w);
    ((ushort4*)Xb)[i] = o;
}

// W [K,N] fp32 row-major -> WT bf16 [N][K]; grid (K/32, N/32), block (32,8)
__global__ void k_cvt_wT(const float* __restrict__ W, ushort* __restrict__ WT,
                         int K, int N) {
    __shared__ float t[32][33];
    int tx = threadIdx.x;        // 0..31
    int ty = threadIdx.y;        // 0..7
    int k0 = blockIdx.x * 32;
    int n0 = blockIdx.y * 32;
#pragma unroll
    for (int i = 0; i < 4; i++)
        t[ty + i * 8][tx] = W[(size_t)(k0 + ty + i * 8) * N + n0 + tx];
    __syncthreads();
#pragma unroll
    for (int i = 0; i < 4; i++)
        WT[(size_t)(n0 + ty + i * 8) * K + k0 + tx] = f2bf(t[tx][ty + i * 8]);
}

// ---------------- MFMA GEMM1: Xb[NN,512] @ WT[512,512](T) -> h1b[NN,512] bf16 ----------
// Block tile 64x128, BK=64, 4 waves in 2x2, wave tile 32x64 (2x4 of 16x16).
#define LDA 72
__global__ __launch_bounds__(256) void k_gemm_mfma(const ushort* __restrict__ Xb,
                                                   const ushort* __restrict__ WT,
                                                   ushort* __restrict__ Y) {
    __shared__ ushort As[64 * LDA];
    __shared__ ushort Bs[128 * LDA];
    int tid = threadIdx.x;
    int lane = tid & 63;
    int wave = tid >> 6;
    int m = lane & 15;
    int q = lane >> 4;
    int wr = wave >> 1;
    int wc = wave & 1;
    int row0 = blockIdx.x * 64;
    int col0 = blockIdx.y * 128;

    f32x4_t acc[2][4];
#pragma unroll
    for (int r = 0; r < 2; r++)
#pragma unroll
        for (int c = 0; c < 4; c++) acc[r][c] = (f32x4_t){0.f, 0.f, 0.f, 0.f};

    int srow = tid >> 3;
    int skk = (tid & 7) * 8;

    for (int kb = 0; kb < 512; kb += 64) {
#pragma unroll
        for (int c_ = 0; c_ < 2; c_++) {
            int row = srow + c_ * 32;
            int grow = row0 + row;
            bf16x8_t v = {0, 0, 0, 0, 0, 0, 0, 0};
            if (grow < NN)
                v = *(const bf16x8_t*)(Xb + (size_t)grow * 512 + kb + skk);
            *(bf16x8_t*)(As + row * LDA + skk) = v;
        }
#pragma unroll
        for (int c_ = 0; c_ < 4; c_++) {
            int n = srow + c_ * 32;
            bf16x8_t v = *(const bf16x8_t*)(WT + (size_t)(col0 + n) * 512 + kb + skk);
            *(bf16x8_t*)(Bs + n * LDA + skk) = v;
        }
        __syncthreads();
#pragma unroll
        for (int kc = 0; kc < 2; kc++) {
            bf16x8_t a[2], b[4];
#pragma unroll
            for (int r = 0; r < 2; r++)
                a[r] = *(const bf16x8_t*)(As + (wr * 32 + r * 16 + m) * LDA + kc * 32 + q * 8);
#pragma unroll
            for (int c = 0; c < 4; c++)
                b[c] = *(const bf16x8_t*)(Bs + (wc * 64 + c * 16 + m) * LDA + kc * 32 + q * 8);
#pragma unroll
            for (int r = 0; r < 2; r++)
#pragma unroll
                for (int c = 0; c < 4; c++)
                    acc[r][c] = __builtin_amdgcn_mfma_f32_16x16x32_bf16(a[r], b[c], acc[r][c], 0, 0, 0);
        }
        __syncthreads();
    }
    // D row = q*4+reg, col = m
#pragma unroll
    for (int r = 0; r < 2; r++) {
#pragma unroll
        for (int c = 0; c < 4; c++) {
#pragma unroll
            for (int reg = 0; reg < 4; reg++) {
                int row = row0 + wr * 32 + r * 16 + q * 4 + reg;
                int col = col0 + wc * 64 + c * 16 + m;
                if (row < NN) Y[(size_t)row * 512 + col] = f2bf(acc[r][c][reg]);
            }
        }
    }
}

// ---------------- MFMA GEMM2: a1b[NN,512] @ W2T[64,512](T) -> h2b[NN,64] bf16 ----------
// Block tile 64x64, BK=64; wave w handles rows [w*16,w*16+16) x 64 cols.
__global__ __launch_bounds__(256) void k_gemm64_mfma(const ushort* __restrict__ Ab,
                                                     const ushort* __restrict__ W2T,
                                                     ushort* __restrict__ Y) {
    __shared__ ushort As[64 * LDA];
    __shared__ ushort Bs[64 * LDA];
    int tid = threadIdx.x;
    int lane = tid & 63;
    int wave = tid >> 6;
    int m = lane & 15;
    int q = lane >> 4;
    int row0 = blockIdx.x * 64;

    f32x4_t acc[4];
#pragma unroll
    for (int c = 0; c < 4; c++) acc[c] = (f32x4_t){0.f, 0.f, 0.f, 0.f};

    int srow = tid >> 3;
    int skk = (tid & 7) * 8;

    for (int kb = 0; kb < 512; kb += 64) {
#pragma unroll
        for (int c_ = 0; c_ < 2; c_++) {
            int row = srow + c_ * 32;
            int grow = row0 + row;
            bf16x8_t v = {0, 0, 0, 0, 0, 0, 0, 0};
            if (grow < NN)
                v = *(const bf16x8_t*)(Ab + (size_t)grow * 512 + kb + skk);
            *(bf16x8_t*)(As + row * LDA + skk) = v;
            bf16x8_t wv = *(const bf16x8_t*)(W2T + (size_t)row * 512 + kb + skk);
            *(bf16x8_t*)(Bs + row * LDA + skk) = wv;
        }
        __syncthreads();
#pragma unroll
        for (int kc = 0; kc < 2; kc++) {
            bf16x8_t a = *(const bf16x8_t*)(As + (wave * 16 + m) * LDA + kc * 32 + q * 8);
#pragma unroll
            for (int c = 0; c < 4; c++) {
                bf16x8_t b = *(const bf16x8_t*)(Bs + (c * 16 + m) * LDA + kc * 32 + q * 8);
                acc[c] = __builtin_amdgcn_mfma_f32_16x16x32_bf16(a, b, acc[c], 0, 0, 0);
            }
        }
        __syncthreads();
    }
#pragma unroll
    for (int c = 0; c < 4; c++) {
#pragma unroll
        for (int reg = 0; reg < 4; reg++) {
            int row = row0 + wave * 16 + q * 4 + reg;
            int col = c * 16 + m;
            if (row < NN) Y[(size_t)row * 64 + col] = f2bf(acc[c][reg]);
        }
    }
}

// ---------------- aggregate layer 1: feature-sliced, XCD-affine ----------------
// grid = NN*8 blocks of 64 threads; slice = blockIdx & 7 rides round-robin
// block->XCD mapping so each XCD gathers only a 1.28 MB column slice of h1b (L2-resident).
__global__ __launch_bounds__(64) void k_agg1(const ushort* __restrict__ h1b,
                                             const int* __restrict__ row_start,
                                             const int* __restrict__ csr_src,
                                             const float* __restrict__ csr_w,
                                             const float* __restrict__ dinv,
                                             const float* __restrict__ b,
                                             ushort* __restrict__ a1b) {
    int bid = blockIdx.x;
    int slice = bid & 7;
    int v = bid >> 3;
    int f = slice * 64 + threadIdx.x;
    float dv = dinv[v];
    float acc = bf2f(h1b[(size_t)v * 512 + f]) * dv * dv;
    int beg = row_start[v], end = row_start[v + 1];
    int sn = 0; float wn = 0.f;
    if (beg < end) { sn = csr_src[beg]; wn = csr_w[beg]; }
    for (int j = beg; j < end; j++) {
        int s = sn; float w = wn;
        if (j + 1 < end) { sn = csr_src[j + 1]; wn = csr_w[j + 1]; }
        acc += bf2f(h1b[(size_t)s * 512 + f]) * w;
    }
    acc += b[f];
    a1b[(size_t)v * 512 + f] = f2bf(acc > 0.f ? acc : 0.f);
}

// ---------------- aggregate layer 2 + bias + log_softmax ----------------
// h2b is 1.28 MB bf16 -> L2-resident everywhere.
__global__ __launch_bounds__(64) void k_agg2_lsm(const ushort* __restrict__ h2b,
                                                 const int* __restrict__ row_start,
                                                 const int* __restrict__ csr_src,
                                                 const float* __restrict__ csr_w,
                                                 const float* __restrict__ dinv,
                                                 const float* __restrict__ b,
                                                 float* __restrict__ out) {
    int v = blockIdx.x;
    int t = threadIdx.x;
    float dv = dinv[v];
    float acc = bf2f(h2b[(size_t)v * 64 + t]) * dv * dv;
    int beg = row_start[v], end = row_start[v + 1];
    int sn = 0; float wn = 0.f;
    if (beg < end) { sn = csr_src[beg]; wn = csr_w[beg]; }
    for (int j = beg; j < end; j++) {
        int s = sn; float w = wn;
        if (j + 1 < end) { sn = csr_src[j + 1]; wn = csr_w[j + 1]; }
        acc += bf2f(h2b[(size_t)s * 64 + t]) * w;
    }
    float h = acc + b[t];
    out[(size_t)v * 64 + t] = h;           // output 0: h
    float m = h;
#pragma unroll
    for (int off = 32; off >= 1; off >>= 1) m = fmaxf(m, __shfl_xor(m, off, 64));
    float e = expf(h - m);
    float ssum = e;
#pragma unroll
    for (int off = 32; off >= 1; off >>= 1) ssum += __shfl_xor(ssum, off, 64);
    out[(size_t)NN * OF + (size_t)v * 64 + t] = h - m - logf(ssum);  // output 1
}

// ---------------- launch ----------------

extern "C" void kernel_launch(void* const* d_in, const int* in_sizes, int n_in,
                              void* d_out, int out_size, void* d_ws, size_t ws_size,
                              hipStream_t stream) {
    const float* x  = (const float*)d_in[0];
    const int*   ei = (const int*)d_in[1];
    const float* W1 = (const float*)d_in[2];
    const float* b1 = (const float*)d_in[3];
    const float* W2 = (const float*)d_in[4];
    const float* b2 = (const float*)d_in[5];
    float* out = (float*)d_out;

    const int E = in_sizes[1] / 2;       // 163840
    const int* src = ei;
    const int* dst = ei + E;

    // workspace carve (256B aligned)
    char* w = (char*)d_ws;
    auto carve = [&](size_t bytes) {
        char* p = w;
        w += (bytes + 255) & ~size_t(255);
        return p;
    };
    ushort* Xb     = (ushort*)carve((size_t)NN * 512 * 2);  // 10.24 MB
    ushort* h1b    = (ushort*)carve((size_t)NN * 512 * 2);  // 10.24 MB
    ushort* a1b    = (ushort*)carve((size_t)NN * 512 * 2);  // 10.24 MB
    ushort* h2b    = (ushort*)carve((size_t)NN * 64 * 2);   // 1.28 MB
    ushort* WTb    = (ushort*)carve((size_t)512 * 512 * 2); // 0.5 MB
    ushort* W2Tb   = (ushort*)carve((size_t)64 * 512 * 2);  // 64 KB
    int*   cnt     = (int*)carve((size_t)NN * 4);
    int*   rstart  = (int*)carve((size_t)(NN + 1) * 4);
    int*   cursor  = (int*)carve((size_t)NN * 4);
    int*   csr_src = (int*)carve((size_t)NE * 4);
    float* csr_w   = (float*)carve((size_t)NE * 4);
    float* dinv    = (float*)carve((size_t)NN * 4);
    (void)ws_size;

    k_zero_int<<<(NN + 255) / 256, 256, 0, stream>>>(cnt, NN);
    k_count<<<(E + 255) / 256, 256, 0, stream>>>(dst, cnt, E);
    k_scan<<<1, 1024, 0, stream>>>(cnt, rstart, cursor, dinv, NN);
    k_fill<<<(E + 255) / 256, 256, 0, stream>>>(src, dst, dinv, cursor, csr_src, csr_w, E);

    k_cvt_x<<<(NN * 512 / 4 + 255) / 256, 256, 0, stream>>>(x, Xb);
    k_cvt_wT<<<dim3(16, 16), dim3(32, 8), 0, stream>>>(W1, WTb, 512, 512);
    k_cvt_wT<<<dim3(16, 2), dim3(32, 8), 0, stream>>>(W2, W2Tb, 512, 64);

    k_gemm_mfma<<<dim3((NN + 63) / 64, 4), 256, 0, stream>>>(Xb, WTb, h1b);
    k_agg1<<<NN * 8, 64, 0, stream>>>(h1b, rstart, csr_src, csr_w, dinv, b1, a1b);
    k_gemm64_mfma<<<(NN + 63) / 64, 256, 0, stream>>>(a1b, W2Tb, h2b);
    k_agg2_lsm<<<NN, 64, 0, stream>>>(h2b, rstart, csr_src, csr_w, dinv, b2, out);
}

// Round 4
// 185.949 us; speedup vs baseline: 1.5150x; 1.1668x over previous
//
#include <hip/hip_runtime.h>
#include <math.h>

// Problem constants (from reference)
#define NN 10000
#define INF 512
#define HF  512
#define OF  64
#define NE  163840

typedef __attribute__((ext_vector_type(8))) short bf16x8_t;   // 8 bf16 = 4 VGPRs
typedef __attribute__((ext_vector_type(4))) float f32x4_t;    // 4 fp32 acc

__device__ inline ushort f2bf(float f) {
    unsigned u = __float_as_uint(f);
    u = (u + 0x7FFF + ((u >> 16) & 1)) >> 16;   // RNE
    return (ushort)u;
}
__device__ inline float bf2f(ushort u) {
    return __uint_as_float(((unsigned)u) << 16);
}

// ---------------- graph preprocessing ----------------

__global__ void k_zero_int(int* __restrict__ p, int n) {
    int i = blockIdx.x * blockDim.x + threadIdx.x;
    if (i < n) p[i] = 0;
}

__global__ void k_count(const int* __restrict__ dst, int* __restrict__ cnt, int E) {
    int e = blockIdx.x * blockDim.x + threadIdx.x;
    if (e < E) atomicAdd(&cnt[dst[e]], 1);
}

// Single-block scan over N counts -> row_start[0..N], cursor copy, dinv = rsqrt(cnt+1).
// shfl wave-scan + 16-entry cross-wave scan: 2 barriers instead of 20.
__global__ __launch_bounds__(1024) void k_scan(const int* __restrict__ cnt,
                                               int* __restrict__ row_start,
                                               int* __restrict__ cursor,
                                               float* __restrict__ dinv, int n) {
    __shared__ int wsum[16];
    int t = threadIdx.x;
    int lane = t & 63, wv = t >> 6;
    const int CH = (n + 1023) >> 10;          // 10 for n=10000
    int begin = t * CH; if (begin > n) begin = n;
    int end = begin + CH; if (end > n) end = n;
    int s = 0;
    for (int i = begin; i < end; i++) s += cnt[i];
    // inclusive wave scan
    int incl = s;
#pragma unroll
    for (int off = 1; off < 64; off <<= 1) {
        int u = __shfl_up(incl, off, 64);
        if (lane >= off) incl += u;
    }
    if (lane == 63) wsum[wv] = incl;
    __syncthreads();
    int woff = 0;
    for (int i = 0; i < wv; i++) woff += wsum[i];   // 16 LDS broadcast reads
    int excl = woff + incl - s;
    for (int i = begin; i < end; i++) {
        row_start[i] = excl;
        cursor[i] = excl;
        int c = cnt[i];
        excl += c;
        dinv[i] = rsqrtf((float)(c + 1));   // +1 self-loop; always > 0
    }
    if (t == 1023) row_start[n] = woff + incl;      // grand total
}

__global__ void k_fill(const int* __restrict__ src, const int* __restrict__ dst,
                       const float* __restrict__ dinv, int* __restrict__ cursor,
                       int* __restrict__ csr_src, float* __restrict__ csr_w, int E) {
    int e = blockIdx.x * blockDim.x + threadIdx.x;
    if (e >= E) return;
    int s = src[e], d = dst[e];
    int p = atomicAdd(&cursor[d], 1);
    csr_src[p] = s;
    csr_w[p] = dinv[s] * dinv[d];
}

// ---------------- bf16 conversions ----------------

__global__ __launch_bounds__(256) void k_cvt_x(const float* __restrict__ X,
                                               ushort* __restrict__ Xb) {
    int i = blockIdx.x * blockDim.x + threadIdx.x;      // float4 index
    float4 v = ((const float4*)X)[i];
    ushort4 o;
    o.x = f2bf(v.x); o.y = f2bf(v.y); o.z = f2bf(v.z); o.w = f2bf(v.w);
    ((ushort4*)Xb)[i] = o;
}

// W [K,N] fp32 row-major -> WT bf16 [N][K]; grid (K/32, N/32), block (32,8)
__global__ void k_cvt_wT(const float* __restrict__ W, ushort* __restrict__ WT,
                         int K, int N) {
    __shared__ float t[32][33];
    int tx = threadIdx.x;
    int ty = threadIdx.y;
    int k0 = blockIdx.x * 32;
    int n0 = blockIdx.y * 32;
#pragma unroll
    for (int i = 0; i < 4; i++)
        t[ty + i * 8][tx] = W[(size_t)(k0 + ty + i * 8) * N + n0 + tx];
    __syncthreads();
#pragma unroll
    for (int i = 0; i < 4; i++)
        WT[(size_t)(n0 + ty + i * 8) * K + k0 + tx] = f2bf(t[tx][ty + i * 8]);
}

// ---------------- MFMA GEMM1: Xb[NN,512] @ WT[512,512](T) -> h1b[NN,512] bf16 ----------
#define LDA 72
__global__ __launch_bounds__(256) void k_gemm_mfma(const ushort* __restrict__ Xb,
                                                   const ushort* __restrict__ WT,
                                                   ushort* __restrict__ Y) {
    __shared__ ushort As[64 * LDA];
    __shared__ ushort Bs[128 * LDA];
    int tid = threadIdx.x;
    int lane = tid & 63;
    int wave = tid >> 6;
    int m = lane & 15;
    int q = lane >> 4;
    int wr = wave >> 1;
    int wc = wave & 1;
    int row0 = blockIdx.x * 64;
    int col0 = blockIdx.y * 128;

    f32x4_t acc[2][4];
#pragma unroll
    for (int r = 0; r < 2; r++)
#pragma unroll
        for (int c = 0; c < 4; c++) acc[r][c] = (f32x4_t){0.f, 0.f, 0.f, 0.f};

    int srow = tid >> 3;
    int skk = (tid & 7) * 8;

    for (int kb = 0; kb < 512; kb += 64) {
#pragma unroll
        for (int c_ = 0; c_ < 2; c_++) {
            int row = srow + c_ * 32;
            int grow = row0 + row;
            bf16x8_t v = {0, 0, 0, 0, 0, 0, 0, 0};
            if (grow < NN)
                v = *(const bf16x8_t*)(Xb + (size_t)grow * 512 + kb + skk);
            *(bf16x8_t*)(As + row * LDA + skk) = v;
        }
#pragma unroll
        for (int c_ = 0; c_ < 4; c_++) {
            int n = srow + c_ * 32;
            bf16x8_t v = *(const bf16x8_t*)(WT + (size_t)(col0 + n) * 512 + kb + skk);
            *(bf16x8_t*)(Bs + n * LDA + skk) = v;
        }
        __syncthreads();
#pragma unroll
        for (int kc = 0; kc < 2; kc++) {
            bf16x8_t a[2], b[4];
#pragma unroll
            for (int r = 0; r < 2; r++)
                a[r] = *(const bf16x8_t*)(As + (wr * 32 + r * 16 + m) * LDA + kc * 32 + q * 8);
#pragma unroll
            for (int c = 0; c < 4; c++)
                b[c] = *(const bf16x8_t*)(Bs + (wc * 64 + c * 16 + m) * LDA + kc * 32 + q * 8);
#pragma unroll
            for (int r = 0; r < 2; r++)
#pragma unroll
                for (int c = 0; c < 4; c++)
                    acc[r][c] = __builtin_amdgcn_mfma_f32_16x16x32_bf16(a[r], b[c], acc[r][c], 0, 0, 0);
        }
        __syncthreads();
    }
#pragma unroll
    for (int r = 0; r < 2; r++) {
#pragma unroll
        for (int c = 0; c < 4; c++) {
#pragma unroll
            for (int reg = 0; reg < 4; reg++) {
                int row = row0 + wr * 32 + r * 16 + q * 4 + reg;
                int col = col0 + wc * 64 + c * 16 + m;
                if (row < NN) Y[(size_t)row * 512 + col] = f2bf(acc[r][c][reg]);
            }
        }
    }
}

// ---------------- MFMA GEMM2: a1b[NN,512] @ W2T[64,512](T) -> h2b[NN,64] bf16 ----------
__global__ __launch_bounds__(256) void k_gemm64_mfma(const ushort* __restrict__ Ab,
                                                     const ushort* __restrict__ W2T,
                                                     ushort* __restrict__ Y) {
    __shared__ ushort As[64 * LDA];
    __shared__ ushort Bs[64 * LDA];
    int tid = threadIdx.x;
    int lane = tid & 63;
    int wave = tid >> 6;
    int m = lane & 15;
    int q = lane >> 4;
    int row0 = blockIdx.x * 64;

    f32x4_t acc[4];
#pragma unroll
    for (int c = 0; c < 4; c++) acc[c] = (f32x4_t){0.f, 0.f, 0.f, 0.f};

    int srow = tid >> 3;
    int skk = (tid & 7) * 8;

    for (int kb = 0; kb < 512; kb += 64) {
#pragma unroll
        for (int c_ = 0; c_ < 2; c_++) {
            int row = srow + c_ * 32;
            int grow = row0 + row;
            bf16x8_t v = {0, 0, 0, 0, 0, 0, 0, 0};
            if (grow < NN)
                v = *(const bf16x8_t*)(Ab + (size_t)grow * 512 + kb + skk);
            *(bf16x8_t*)(As + row * LDA + skk) = v;
            bf16x8_t wv = *(const bf16x8_t*)(W2T + (size_t)row * 512 + kb + skk);
            *(bf16x8_t*)(Bs + row * LDA + skk) = wv;
        }
        __syncthreads();
#pragma unroll
        for (int kc = 0; kc < 2; kc++) {
            bf16x8_t a = *(const bf16x8_t*)(As + (wave * 16 + m) * LDA + kc * 32 + q * 8);
#pragma unroll
            for (int c = 0; c < 4; c++) {
                bf16x8_t b = *(const bf16x8_t*)(Bs + (c * 16 + m) * LDA + kc * 32 + q * 8);
                acc[c] = __builtin_amdgcn_mfma_f32_16x16x32_bf16(a, b, acc[c], 0, 0, 0);
            }
        }
        __syncthreads();
    }
#pragma unroll
    for (int c = 0; c < 4; c++) {
#pragma unroll
        for (int reg = 0; reg < 4; reg++) {
            int row = row0 + wave * 16 + q * 4 + reg;
            int col = c * 16 + m;
            if (row < NN) Y[(size_t)row * 64 + col] = f2bf(acc[c][reg]);
        }
    }
}

// ---------------- aggregate layer 1: XCD-affine slices + 8-deep MLP ----------------
// grid NN*8 blocks of 64 (1 wave). slice = bid&7 rides round-robin block->XCD map:
// each XCD gathers only a 1.28 MB column slice of h1b (L2-resident; R2: FETCH 145->16 MB).
// Edge (idx,w) staged 64-at-a-time via one coalesced load into LDS; inner loop
// unrolled x8 with 8 independent accumulators so 8 gathers are in flight (latency fix).
__global__ __launch_bounds__(64) void k_agg1(const ushort* __restrict__ h1b,
                                             const int* __restrict__ row_start,
                                             const int* __restrict__ csr_src,
                                             const float* __restrict__ csr_w,
                                             const float* __restrict__ dinv,
                                             const float* __restrict__ b,
                                             ushort* __restrict__ a1b) {
    __shared__ int   sidx[64];
    __shared__ float swt[64];
    int bid = blockIdx.x;
    int slice = bid & 7;
    int v = bid >> 3;
    int t = threadIdx.x;
    int f = slice * 64 + t;
    float dv = dinv[v];
    int beg = row_start[v], end = row_start[v + 1];
    float acc[8];
#pragma unroll
    for (int k = 0; k < 8; k++) acc[k] = 0.f;
    acc[0] = bf2f(h1b[(size_t)v * 512 + f]) * (dv * dv);   // self-loop

    for (int chunk = beg; chunk < end; chunk += 64) {
        int j = chunk + t;
        if (j < end) { sidx[t] = csr_src[j]; swt[t] = csr_w[j]; }
        else         { sidx[t] = 0;          swt[t] = 0.f; }
        __syncthreads();
        int n = end - chunk; if (n > 64) n = 64;
        int nr = (n + 7) & ~7;                 // round to 8; extras have w=0
        for (int i = 0; i < nr; i += 8) {
            int   sK[8]; float wK[8];
#pragma unroll
            for (int k = 0; k < 8; k++) { sK[k] = sidx[i + k]; wK[k] = swt[i + k]; }
#pragma unroll
            for (int k = 0; k < 8; k++)
                acc[k] += bf2f(h1b[(size_t)sK[k] * 512 + f]) * wK[k];
        }
        __syncthreads();
    }
    float total = ((acc[0] + acc[1]) + (acc[2] + acc[3])) +
                  ((acc[4] + acc[5]) + (acc[6] + acc[7]));
    total += b[f];
    a1b[(size_t)v * 512 + f] = f2bf(total > 0.f ? total : 0.f);
}

// ---------------- aggregate layer 2 + bias + log_softmax (same MLP fix) ----------------
__global__ __launch_bounds__(64) void k_agg2_lsm(const ushort* __restrict__ h2b,
                                                 const int* __restrict__ row_start,
                                                 const int* __restrict__ csr_src,
                                                 const float* __restrict__ csr_w,
                                                 const float* __restrict__ dinv,
                                                 const float* __restrict__ b,
                                                 float* __restrict__ out) {
    __shared__ int   sidx[64];
    __shared__ float swt[64];
    int v = blockIdx.x;
    int t = threadIdx.x;
    float dv = dinv[v];
    int beg = row_start[v], end = row_start[v + 1];
    float acc[8];
#pragma unroll
    for (int k = 0; k < 8; k++) acc[k] = 0.f;
    acc[0] = bf2f(h2b[(size_t)v * 64 + t]) * (dv * dv);

    for (int chunk = beg; chunk < end; chunk += 64) {
        int j = chunk + t;
        if (j < end) { sidx[t] = csr_src[j]; swt[t] = csr_w[j]; }
        else         { sidx[t] = 0;          swt[t] = 0.f; }
        __syncthreads();
        int n = end - chunk; if (n > 64) n = 64;
        int nr = (n + 7) & ~7;
        for (int i = 0; i < nr; i += 8) {
            int   sK[8]; float wK[8];
#pragma unroll
            for (int k = 0; k < 8; k++) { sK[k] = sidx[i + k]; wK[k] = swt[i + k]; }
#pragma unroll
            for (int k = 0; k < 8; k++)
                acc[k] += bf2f(h2b[(size_t)sK[k] * 64 + t]) * wK[k];
        }
        __syncthreads();
    }
    float h = ((acc[0] + acc[1]) + (acc[2] + acc[3])) +
              ((acc[4] + acc[5]) + (acc[6] + acc[7]));
    h += b[t];
    out[(size_t)v * 64 + t] = h;           // output 0: h
    float m = h;
#pragma unroll
    for (int off = 32; off >= 1; off >>= 1) m = fmaxf(m, __shfl_xor(m, off, 64));
    float e = expf(h - m);
    float ssum = e;
#pragma unroll
    for (int off = 32; off >= 1; off >>= 1) ssum += __shfl_xor(ssum, off, 64);
    out[(size_t)NN * OF + (size_t)v * 64 + t] = h - m - logf(ssum);  // output 1
}

// ---------------- launch ----------------

extern "C" void kernel_launch(void* const* d_in, const int* in_sizes, int n_in,
                              void* d_out, int out_size, void* d_ws, size_t ws_size,
                              hipStream_t stream) {
    const float* x  = (const float*)d_in[0];
    const int*   ei = (const int*)d_in[1];
    const float* W1 = (const float*)d_in[2];
    const float* b1 = (const float*)d_in[3];
    const float* W2 = (const float*)d_in[4];
    const float* b2 = (const float*)d_in[5];
    float* out = (float*)d_out;

    const int E = in_sizes[1] / 2;       // 163840
    const int* src = ei;
    const int* dst = ei + E;

    char* w = (char*)d_ws;
    auto carve = [&](size_t bytes) {
        char* p = w;
        w += (bytes + 255) & ~size_t(255);
        return p;
    };
    ushort* Xb     = (ushort*)carve((size_t)NN * 512 * 2);
    ushort* h1b    = (ushort*)carve((size_t)NN * 512 * 2);
    ushort* a1b    = (ushort*)carve((size_t)NN * 512 * 2);
    ushort* h2b    = (ushort*)carve((size_t)NN * 64 * 2);
    ushort* WTb    = (ushort*)carve((size_t)512 * 512 * 2);
    ushort* W2Tb   = (ushort*)carve((size_t)64 * 512 * 2);
    int*   cnt     = (int*)carve((size_t)NN * 4);
    int*   rstart  = (int*)carve((size_t)(NN + 1) * 4);
    int*   cursor  = (int*)carve((size_t)NN * 4);
    int*   csr_src = (int*)carve((size_t)NE * 4);
    float* csr_w   = (float*)carve((size_t)NE * 4);
    float* dinv    = (float*)carve((size_t)NN * 4);
    (void)ws_size;

    k_zero_int<<<(NN + 255) / 256, 256, 0, stream>>>(cnt, NN);
    k_count<<<(E + 255) / 256, 256, 0, stream>>>(dst, cnt, E);
    k_scan<<<1, 1024, 0, stream>>>(cnt, rstart, cursor, dinv, NN);
    k_fill<<<(E + 255) / 256, 256, 0, stream>>>(src, dst, dinv, cursor, csr_src, csr_w, E);

    k_cvt_x<<<(NN * 512 / 4 + 255) / 256, 256, 0, stream>>>(x, Xb);
    k_cvt_wT<<<dim3(16, 16), dim3(32, 8), 0, stream>>>(W1, WTb, 512, 512);
    k_cvt_wT<<<dim3(16, 2), dim3(32, 8), 0, stream>>>(W2, W2Tb, 512, 64);

    k_gemm_mfma<<<dim3((NN + 63) / 64, 4), 256, 0, stream>>>(Xb, WTb, h1b);
    k_agg1<<<NN * 8, 64, 0, stream>>>(h1b, rstart, csr_src, csr_w, dinv, b1, a1b);
    k_gemm64_mfma<<<(NN + 63) / 64, 256, 0, stream>>>(a1b, W2Tb, h2b);
    k_agg2_lsm<<<NN, 64, 0, stream>>>(h2b, rstart, csr_src, csr_w, dinv, b2, out);
}